// Round 7
// baseline (117.806 us; speedup 1.0000x reference)
//
#include <hip/hip_runtime.h>
#include <hip/hip_fp16.h>

#define B_ 2
#define C_ 4
#define H_ 512
#define W_ 512
#define V_ 100000
#define F_ 200000
#define A_ 8

#define HW_   (H_ * W_)                 // 262144 = 2^18
#define NPIX  (B_ * C_ * H_ * W_)       // 2,097,152
#define PLANE ((size_t)NPIX * 3)

typedef float f32x4 __attribute__((ext_vector_type(4)));
typedef int   i32x4 __attribute__((ext_vector_type(4)));

// ---------------------------------------------------------------------------
// Prep 1 (fused): face normals (B*F) + faces64 pack (F)
// ---------------------------------------------------------------------------
__global__ void k_prep1(const float* __restrict__ vertex_pos,
                        const int* __restrict__ faces,
                        float* __restrict__ face_normal,
                        unsigned long long* __restrict__ faces64) {
    int t = blockIdx.x * blockDim.x + threadIdx.x;
    if (t >= B_ * F_) return;
    int b = t / F_;
    int f = t - b * F_;
    int i0 = faces[f * 3 + 0];
    int i1 = faces[f * 3 + 1];
    int i2 = faces[f * 3 + 2];
    if (b == 0) {
        faces64[f] = (unsigned long long)(unsigned)i0 |
                     ((unsigned long long)(unsigned)i1 << 17) |
                     ((unsigned long long)(unsigned)i2 << 34);
    }
    const float* vp = vertex_pos + (size_t)b * V_ * 3;
    float p0x = vp[i0 * 3 + 0], p0y = vp[i0 * 3 + 1], p0z = vp[i0 * 3 + 2];
    float p1x = vp[i1 * 3 + 0], p1y = vp[i1 * 3 + 1], p1z = vp[i1 * 3 + 2];
    float p2x = vp[i2 * 3 + 0], p2y = vp[i2 * 3 + 1], p2z = vp[i2 * 3 + 2];
    float e1x = p1x - p0x, e1y = p1y - p0y, e1z = p1z - p0z;
    float e2x = p2x - p0x, e2y = p2y - p0y, e2z = p2z - p0z;
    face_normal[(size_t)t * 3 + 0] = e1y * e2z - e1z * e2y;
    face_normal[(size_t)t * 3 + 1] = e1z * e2x - e1x * e2z;
    face_normal[(size_t)t * 3 + 2] = e1x * e2y - e1y * e2x;
}

// ---------------------------------------------------------------------------
// Prep 2 (fused):
//   scr16[bc*V+v] = uint2{ h2(sx,sy), h2(sz,0) }                 (8 B)
//   pn16[b*V+v]   = uint4{ h2(px,py), h2(pz,nx), h2(ny,nz), 0 }  (16 B)
// ---------------------------------------------------------------------------
__global__ void k_prep2(const float* __restrict__ vertex_pos,
                        const float* __restrict__ intrinsics,
                        const float* __restrict__ extrinsics,
                        const float* __restrict__ face_normal,
                        const int* __restrict__ vert_adj_faces,
                        const float* __restrict__ vert_adj_weights,
                        uint2* __restrict__ scr16,
                        uint4* __restrict__ pn16) {
    int t = blockIdx.x * blockDim.x + threadIdx.x;
    if (t >= B_ * C_ * V_) return;
    {   // screen-space projection -> fp16
        int v = t % V_;
        int bc = t / V_;
        int b = bc / C_;
        const float* vp = vertex_pos + ((size_t)b * V_ + v) * 3;
        float x = vp[0], y = vp[1], z = vp[2];
        const float* E = extrinsics + (size_t)bc * 12;
        float cv0 = x * E[0] + y * E[1] + z * E[2]  + E[3];
        float cv1 = x * E[4] + y * E[5] + z * E[6]  + E[7];
        float cv2 = x * E[8] + y * E[9] + z * E[10] + E[11];
        const float* K = intrinsics + (size_t)bc * 9;
        float i0 = cv0 * K[0] + cv1 * K[1] + cv2 * K[2];
        float i1 = cv0 * K[3] + cv1 * K[4] + cv2 * K[5];
        float i2 = cv0 * K[6] + cv1 * K[7] + cv2 * K[8];
        __half2 s01 = __floats2half2_rn(i0 / i2, i1 / i2);
        __half2 s2  = __floats2half2_rn(i2, 0.f);
        scr16[t] = make_uint2(*reinterpret_cast<unsigned int*>(&s01),
                              *reinterpret_cast<unsigned int*>(&s2));
    }
    if (t < B_ * V_) {  // vertex normal + fp16 pack (16B-aligned record)
        int b = t / V_;
        int v = t - b * V_;
        const int* adj = vert_adj_faces + (size_t)v * A_;
        const float* wt = vert_adj_weights + (size_t)v * A_;
        const float* fn = face_normal + (size_t)b * F_ * 3;
        float ax = 0.f, ay = 0.f, az = 0.f;
#pragma unroll
        for (int a = 0; a < A_; ++a) {
            int f = adj[a];
            float w = wt[a];
            ax += w * fn[(size_t)f * 3 + 0];
            ay += w * fn[(size_t)f * 3 + 1];
            az += w * fn[(size_t)f * 3 + 2];
        }
        const float* p = vertex_pos + (size_t)t * 3;
        __half2 h0 = __floats2half2_rn(p[0], p[1]);
        __half2 h1 = __floats2half2_rn(p[2], ax);
        __half2 h2 = __floats2half2_rn(ay, az);
        pn16[t] = make_uint4(*reinterpret_cast<unsigned int*>(&h0),
                             *reinterpret_cast<unsigned int*>(&h1),
                             *reinterpret_cast<unsigned int*>(&h2), 0u);
    }
}

// ---------------------------------------------------------------------------
// Pixel kernel: 4 px/thread, XCD swizzle (1 view per XCD -> 4.0 MB L2 set),
// all stream I/O as 16B NT ops, gathers: dwordx2 + dwordx4 + dwordx2.
// ---------------------------------------------------------------------------
__global__ __launch_bounds__(256) void k_pixel4(
        const unsigned long long* __restrict__ faces64,
        const float* __restrict__ inverse_extrinsics,
        const int* __restrict__ face_id,
        const float* __restrict__ bary,
        const uint4* __restrict__ pn16,
        const uint2* __restrict__ scr16,
        float* __restrict__ out) {
    // 2048 blocks, 8 XCDs -> 256 contiguous blocks per XCD = exactly one view
    int nb = gridDim.x;
    int bid = blockIdx.x;
    int swz = (bid & 7) * (nb >> 3) + (bid >> 3);

    int base = (swz * 256 + (int)threadIdx.x) * 4;   // first of 4 pixels
    int bc = base >> 18;        // HW_ = 2^18
    int b  = bc >> 2;           // C_ == 4

    const float* ie = inverse_extrinsics + (size_t)bc * 16;
    float iw = ie[15];
    float ox = ie[3] / iw, oy = ie[7] / iw, oz = ie[11] / iw;

    i32x4 fid4 = __builtin_nontemporal_load((const i32x4*)(face_id + base));
    int fidv[4] = {fid4.x, fid4.y, fid4.z, fid4.w};

    const f32x4* bp = (const f32x4*)(bary + (size_t)base * 3);  // 48B-aligned
    f32x4 q0 = __builtin_nontemporal_load(bp + 0);
    f32x4 q1 = __builtin_nontemporal_load(bp + 1);
    f32x4 q2 = __builtin_nontemporal_load(bp + 2);
    float bw[4][3] = {{q0.x, q0.y, q0.z},
                      {q0.w, q1.x, q1.y},
                      {q1.z, q1.w, q2.x},
                      {q2.y, q2.z, q2.w}};

    float fg[4], dep[4];
    float pos[4][3], nrm[4][3], sc[4][3];

#pragma unroll
    for (int k = 0; k < 4; ++k) {
        int fid = fidv[k];
        float w0 = bw[k][0], w1 = bw[k][1], w2 = bw[k][2];
        if (fid >= 0) {
            unsigned long long f3 = faces64[fid];
            int i0 = (int)(f3 & 0x1FFFF);
            int i1 = (int)((f3 >> 17) & 0x1FFFF);
            int i2 = (int)((f3 >> 34) & 0x1FFFF);

            size_t basev = (size_t)b * V_;
            uint4 A  = pn16[basev + i0];
            uint4 Bv = pn16[basev + i1];
            uint4 Cv = pn16[basev + i2];

            float2 af0 = __half22float2(*reinterpret_cast<__half2*>(&A.x));
            float2 af1 = __half22float2(*reinterpret_cast<__half2*>(&A.y));
            float2 af2 = __half22float2(*reinterpret_cast<__half2*>(&A.z));
            float2 bf0 = __half22float2(*reinterpret_cast<__half2*>(&Bv.x));
            float2 bf1 = __half22float2(*reinterpret_cast<__half2*>(&Bv.y));
            float2 bf2 = __half22float2(*reinterpret_cast<__half2*>(&Bv.z));
            float2 cf0 = __half22float2(*reinterpret_cast<__half2*>(&Cv.x));
            float2 cf1 = __half22float2(*reinterpret_cast<__half2*>(&Cv.y));
            float2 cf2 = __half22float2(*reinterpret_cast<__half2*>(&Cv.z));

            float px = w0 * af0.x + w1 * bf0.x + w2 * cf0.x;
            float py = w0 * af0.y + w1 * bf0.y + w2 * cf0.y;
            float pz = w0 * af1.x + w1 * bf1.x + w2 * cf1.x;
            float nx = w0 * af1.y + w1 * bf1.y + w2 * cf1.y;
            float ny = w0 * af2.x + w1 * bf2.x + w2 * cf2.x;
            float nz = w0 * af2.y + w1 * bf2.y + w2 * cf2.y;

            size_t sbase = (size_t)bc * V_;
            uint2 S0 = scr16[sbase + i0];
            uint2 S1 = scr16[sbase + i1];
            uint2 S2 = scr16[sbase + i2];
            float2 s0a = __half22float2(*reinterpret_cast<__half2*>(&S0.x));
            float2 s0b = __half22float2(*reinterpret_cast<__half2*>(&S0.y));
            float2 s1a = __half22float2(*reinterpret_cast<__half2*>(&S1.x));
            float2 s1b = __half22float2(*reinterpret_cast<__half2*>(&S1.y));
            float2 s2a = __half22float2(*reinterpret_cast<__half2*>(&S2.x));
            float2 s2b = __half22float2(*reinterpret_cast<__half2*>(&S2.y));
            float sx = w0 * s0a.x + w1 * s1a.x + w2 * s2a.x;
            float sy = w0 * s0a.y + w1 * s1a.y + w2 * s2a.y;
            float sz = w0 * s0b.x + w1 * s1b.x + w2 * s2b.x;

            float nlen = fmaxf(sqrtf(nx * nx + ny * ny + nz * nz), 1e-12f);
            nx /= nlen; ny /= nlen; nz /= nlen;

            float dx = ox - px, dy = oy - py, dz = oz - pz;
            fg[k] = 1.f;
            dep[k] = sqrtf(dx * dx + dy * dy + dz * dz);
            pos[k][0] = px; pos[k][1] = py; pos[k][2] = pz;
            nrm[k][0] = nx; nrm[k][1] = ny; nrm[k][2] = nz;
            sc[k][0] = sx; sc[k][1] = sy; sc[k][2] = sz;
        } else {
            fg[k] = 0.f; dep[k] = 0.f;
            pos[k][0] = pos[k][1] = pos[k][2] = 0.f;
            nrm[k][0] = nrm[k][1] = nrm[k][2] = 0.f;
            sc[k][0] = sc[k][1] = sc[k][2] = 0.f;
        }
    }

    // 12 floats per plane per thread, written as 3x 16B NT stores (48B-aligned)
    size_t o = (size_t)base * 3;
    f32x4* o0 = (f32x4*)(out + 0 * PLANE + o);
    f32x4* o1 = (f32x4*)(out + 1 * PLANE + o);
    f32x4* o2 = (f32x4*)(out + 2 * PLANE + o);
    f32x4* o3 = (f32x4*)(out + 3 * PLANE + o);
    f32x4* o4 = (f32x4*)(out + 4 * PLANE + o);

    __builtin_nontemporal_store((f32x4){fg[0], fg[0], fg[0], fg[1]}, o0 + 0);
    __builtin_nontemporal_store((f32x4){fg[1], fg[1], fg[2], fg[2]}, o0 + 1);
    __builtin_nontemporal_store((f32x4){fg[2], fg[3], fg[3], fg[3]}, o0 + 2);

    __builtin_nontemporal_store((f32x4){pos[0][0], pos[0][1], pos[0][2], pos[1][0]}, o1 + 0);
    __builtin_nontemporal_store((f32x4){pos[1][1], pos[1][2], pos[2][0], pos[2][1]}, o1 + 1);
    __builtin_nontemporal_store((f32x4){pos[2][2], pos[3][0], pos[3][1], pos[3][2]}, o1 + 2);

    __builtin_nontemporal_store((f32x4){nrm[0][0], nrm[0][1], nrm[0][2], nrm[1][0]}, o2 + 0);
    __builtin_nontemporal_store((f32x4){nrm[1][1], nrm[1][2], nrm[2][0], nrm[2][1]}, o2 + 1);
    __builtin_nontemporal_store((f32x4){nrm[2][2], nrm[3][0], nrm[3][1], nrm[3][2]}, o2 + 2);

    __builtin_nontemporal_store((f32x4){dep[0], dep[0], dep[0], dep[1]}, o3 + 0);
    __builtin_nontemporal_store((f32x4){dep[1], dep[1], dep[2], dep[2]}, o3 + 1);
    __builtin_nontemporal_store((f32x4){dep[2], dep[3], dep[3], dep[3]}, o3 + 2);

    __builtin_nontemporal_store((f32x4){sc[0][0], sc[0][1], sc[0][2], sc[1][0]}, o4 + 0);
    __builtin_nontemporal_store((f32x4){sc[1][1], sc[1][2], sc[2][0], sc[2][1]}, o4 + 1);
    __builtin_nontemporal_store((f32x4){sc[2][2], sc[3][0], sc[3][1], sc[3][2]}, o4 + 2);
}

// ---------------------------------------------------------------------------
extern "C" void kernel_launch(void* const* d_in, const int* in_sizes, int n_in,
                              void* d_out, int out_size, void* d_ws, size_t ws_size,
                              hipStream_t stream) {
    const float* vertex_pos         = (const float*)d_in[0];
    const int*   faces              = (const int*)  d_in[1];
    const int*   vert_adj_faces     = (const int*)  d_in[2];
    const float* vert_adj_weights   = (const float*)d_in[3];
    const float* intrinsics         = (const float*)d_in[4];
    const float* extrinsics         = (const float*)d_in[5];
    const float* inverse_extrinsics = (const float*)d_in[6];
    const int*   face_id            = (const int*)  d_in[7];
    const float* barycentrics       = (const float*)d_in[8];
    float* out = (float*)d_out;
    char* ws = (char*)d_ws;
    const int TPB = 256;

    // layout: fn 4.8MB | faces64 1.6MB | pn16 3.2MB | scr16 6.4MB = 16.0MB
    float*              fn      = (float*)             (ws + 0);
    unsigned long long* faces64 = (unsigned long long*)(ws + 4800000);
    uint4*              pn16    = (uint4*)             (ws + 6400000);
    uint2*              scr16   = (uint2*)             (ws + 9600000);

    hipLaunchKernelGGL(k_prep1, dim3((B_ * F_ + TPB - 1) / TPB), dim3(TPB), 0, stream,
                       vertex_pos, faces, fn, faces64);
    hipLaunchKernelGGL(k_prep2, dim3((B_ * C_ * V_ + TPB - 1) / TPB), dim3(TPB), 0, stream,
                       vertex_pos, intrinsics, extrinsics, fn,
                       vert_adj_faces, vert_adj_weights, scr16, pn16);
    hipLaunchKernelGGL(k_pixel4, dim3(NPIX / 4 / TPB), dim3(TPB), 0, stream,
                       faces64, inverse_extrinsics, face_id, barycentrics,
                       pn16, scr16, out);
}

// Round 8
// 101.898 us; speedup vs baseline: 1.1561x; 1.1561x over previous
//
#include <hip/hip_runtime.h>
#include <hip/hip_fp16.h>
#include <string.h>

#define B_ 2
#define C_ 4
#define H_ 512
#define W_ 512
#define V_ 100000
#define F_ 200000
#define A_ 8

#define HW_   (H_ * W_)                 // 262144 = 2^18
#define NPIX  (B_ * C_ * H_ * W_)       // 2,097,152
#define PLANE ((size_t)NPIX * 3)
#define PXB   512                       // pixels per block (2 per thread)

typedef float f32x4 __attribute__((ext_vector_type(4)));

__device__ __forceinline__ float2 unpack2f(double d) {
    float2 t;
    memcpy(&t, &d, 8);
    return t;
}

// ---------------------------------------------------------------------------
// Prep 1 (fused): face normals (B*F) + faces64 pack (F)
// ---------------------------------------------------------------------------
__global__ void k_prep1(const float* __restrict__ vertex_pos,
                        const int* __restrict__ faces,
                        float* __restrict__ face_normal,
                        unsigned long long* __restrict__ faces64) {
    int t = blockIdx.x * blockDim.x + threadIdx.x;
    if (t >= B_ * F_) return;
    int b = t / F_;
    int f = t - b * F_;
    int i0 = faces[f * 3 + 0];
    int i1 = faces[f * 3 + 1];
    int i2 = faces[f * 3 + 2];
    if (b == 0) {
        faces64[f] = (unsigned long long)(unsigned)i0 |
                     ((unsigned long long)(unsigned)i1 << 17) |
                     ((unsigned long long)(unsigned)i2 << 34);
    }
    const float* vp = vertex_pos + (size_t)b * V_ * 3;
    float p0x = vp[i0 * 3 + 0], p0y = vp[i0 * 3 + 1], p0z = vp[i0 * 3 + 2];
    float p1x = vp[i1 * 3 + 0], p1y = vp[i1 * 3 + 1], p1z = vp[i1 * 3 + 2];
    float p2x = vp[i2 * 3 + 0], p2y = vp[i2 * 3 + 1], p2z = vp[i2 * 3 + 2];
    float e1x = p1x - p0x, e1y = p1y - p0y, e1z = p1z - p0z;
    float e2x = p2x - p0x, e2y = p2y - p0y, e2z = p2z - p0z;
    face_normal[(size_t)t * 3 + 0] = e1y * e2z - e1z * e2y;
    face_normal[(size_t)t * 3 + 1] = e1z * e2x - e1x * e2z;
    face_normal[(size_t)t * 3 + 2] = e1x * e2y - e1y * e2x;
}

// ---------------------------------------------------------------------------
// Prep 2 (fused):
//   scr16[bc*V+v] = uint2{ h2(sx,sy), h2(sz,0) }                 (8 B)
//   pn16[b*V+v]   = uint4{ h2(px,py), h2(pz,nx), h2(ny,nz), 0 }  (16 B)
// ---------------------------------------------------------------------------
__global__ void k_prep2(const float* __restrict__ vertex_pos,
                        const float* __restrict__ intrinsics,
                        const float* __restrict__ extrinsics,
                        const float* __restrict__ face_normal,
                        const int* __restrict__ vert_adj_faces,
                        const float* __restrict__ vert_adj_weights,
                        uint2* __restrict__ scr16,
                        uint4* __restrict__ pn16) {
    int t = blockIdx.x * blockDim.x + threadIdx.x;
    if (t >= B_ * C_ * V_) return;
    {   // screen-space projection -> fp16
        int v = t % V_;
        int bc = t / V_;
        int b = bc / C_;
        const float* vp = vertex_pos + ((size_t)b * V_ + v) * 3;
        float x = vp[0], y = vp[1], z = vp[2];
        const float* E = extrinsics + (size_t)bc * 12;
        float cv0 = x * E[0] + y * E[1] + z * E[2]  + E[3];
        float cv1 = x * E[4] + y * E[5] + z * E[6]  + E[7];
        float cv2 = x * E[8] + y * E[9] + z * E[10] + E[11];
        const float* K = intrinsics + (size_t)bc * 9;
        float i0 = cv0 * K[0] + cv1 * K[1] + cv2 * K[2];
        float i1 = cv0 * K[3] + cv1 * K[4] + cv2 * K[5];
        float i2 = cv0 * K[6] + cv1 * K[7] + cv2 * K[8];
        __half2 s01 = __floats2half2_rn(i0 / i2, i1 / i2);
        __half2 s2  = __floats2half2_rn(i2, 0.f);
        scr16[t] = make_uint2(*reinterpret_cast<unsigned int*>(&s01),
                              *reinterpret_cast<unsigned int*>(&s2));
    }
    if (t < B_ * V_) {  // vertex normal + fp16 pack (16B-aligned record)
        int b = t / V_;
        int v = t - b * V_;
        const int* adj = vert_adj_faces + (size_t)v * A_;
        const float* wt = vert_adj_weights + (size_t)v * A_;
        const float* fn = face_normal + (size_t)b * F_ * 3;
        float ax = 0.f, ay = 0.f, az = 0.f;
#pragma unroll
        for (int a = 0; a < A_; ++a) {
            int f = adj[a];
            float w = wt[a];
            ax += w * fn[(size_t)f * 3 + 0];
            ay += w * fn[(size_t)f * 3 + 1];
            az += w * fn[(size_t)f * 3 + 2];
        }
        const float* p = vertex_pos + (size_t)t * 3;
        __half2 h0 = __floats2half2_rn(p[0], p[1]);
        __half2 h1 = __floats2half2_rn(p[2], ax);
        __half2 h2 = __floats2half2_rn(ay, az);
        pn16[t] = make_uint4(*reinterpret_cast<unsigned int*>(&h0),
                             *reinterpret_cast<unsigned int*>(&h1),
                             *reinterpret_cast<unsigned int*>(&h2), 0u);
    }
}

// ---------------------------------------------------------------------------
// Pixel kernel: 2 px/thread, XCD swizzle, fp16 tables, LDS-staged output
// with full-line cooperative NT stores (fixes NT partial-line write ampl.).
// ---------------------------------------------------------------------------
__global__ __launch_bounds__(256) void k_pixel_lds(
        const unsigned long long* __restrict__ faces64,
        const float* __restrict__ inverse_extrinsics,
        const int* __restrict__ face_id,
        const float* __restrict__ bary,
        const uint4* __restrict__ pn16,
        const uint2* __restrict__ scr16,
        float* __restrict__ out) {
    __shared__ float lds[5][PXB * 3];   // 5 x 6144B = 30720B

    // 4096 blocks, 8 XCDs -> 512 contiguous blocks per XCD = exactly one view
    int nb = gridDim.x;
    int bid = blockIdx.x;
    int swz = (bid & 7) * (nb >> 3) + (bid >> 3);
    int tid = threadIdx.x;

    int base = swz * PXB + tid * 2;     // first of 2 pixels
    int bc = base >> 18;                // HW_ = 2^18
    int b  = bc >> 2;                   // C_ == 4

    const float* ie = inverse_extrinsics + (size_t)bc * 16;
    float iw = ie[15];
    float ox = ie[3] / iw, oy = ie[7] / iw, oz = ie[11] / iw;

    long long fid2 = __builtin_nontemporal_load((const long long*)(face_id + base));
    int fidv[2] = { (int)(fid2 & 0xFFFFFFFFll), (int)(fid2 >> 32) };

    const double* bp = (const double*)(bary + (size_t)base * 3);  // 8B-aligned
    float2 q0 = unpack2f(__builtin_nontemporal_load(bp + 0));
    float2 q1 = unpack2f(__builtin_nontemporal_load(bp + 1));
    float2 q2 = unpack2f(__builtin_nontemporal_load(bp + 2));
    float bw[2][3] = {{q0.x, q0.y, q1.x}, {q1.y, q2.x, q2.y}};

    float fg[2], dep[2];
    float pos[2][3], nrm[2][3], sc[2][3];

#pragma unroll
    for (int k = 0; k < 2; ++k) {
        int fid = fidv[k];
        float w0 = bw[k][0], w1 = bw[k][1], w2 = bw[k][2];
        if (fid >= 0) {
            unsigned long long f3 = faces64[fid];
            int i0 = (int)(f3 & 0x1FFFF);
            int i1 = (int)((f3 >> 17) & 0x1FFFF);
            int i2 = (int)((f3 >> 34) & 0x1FFFF);

            size_t basev = (size_t)b * V_;
            uint4 A  = pn16[basev + i0];
            uint4 Bv = pn16[basev + i1];
            uint4 Cv = pn16[basev + i2];

            float2 af0 = __half22float2(*reinterpret_cast<__half2*>(&A.x));
            float2 af1 = __half22float2(*reinterpret_cast<__half2*>(&A.y));
            float2 af2 = __half22float2(*reinterpret_cast<__half2*>(&A.z));
            float2 bf0 = __half22float2(*reinterpret_cast<__half2*>(&Bv.x));
            float2 bf1 = __half22float2(*reinterpret_cast<__half2*>(&Bv.y));
            float2 bf2 = __half22float2(*reinterpret_cast<__half2*>(&Bv.z));
            float2 cf0 = __half22float2(*reinterpret_cast<__half2*>(&Cv.x));
            float2 cf1 = __half22float2(*reinterpret_cast<__half2*>(&Cv.y));
            float2 cf2 = __half22float2(*reinterpret_cast<__half2*>(&Cv.z));

            float px = w0 * af0.x + w1 * bf0.x + w2 * cf0.x;
            float py = w0 * af0.y + w1 * bf0.y + w2 * cf0.y;
            float pz = w0 * af1.x + w1 * bf1.x + w2 * cf1.x;
            float nx = w0 * af1.y + w1 * bf1.y + w2 * cf1.y;
            float ny = w0 * af2.x + w1 * bf2.x + w2 * cf2.x;
            float nz = w0 * af2.y + w1 * bf2.y + w2 * cf2.y;

            size_t sbase = (size_t)bc * V_;
            uint2 S0 = scr16[sbase + i0];
            uint2 S1 = scr16[sbase + i1];
            uint2 S2 = scr16[sbase + i2];
            float2 s0a = __half22float2(*reinterpret_cast<__half2*>(&S0.x));
            float2 s0b = __half22float2(*reinterpret_cast<__half2*>(&S0.y));
            float2 s1a = __half22float2(*reinterpret_cast<__half2*>(&S1.x));
            float2 s1b = __half22float2(*reinterpret_cast<__half2*>(&S1.y));
            float2 s2a = __half22float2(*reinterpret_cast<__half2*>(&S2.x));
            float2 s2b = __half22float2(*reinterpret_cast<__half2*>(&S2.y));
            float sx = w0 * s0a.x + w1 * s1a.x + w2 * s2a.x;
            float sy = w0 * s0a.y + w1 * s1a.y + w2 * s2a.y;
            float sz = w0 * s0b.x + w1 * s1b.x + w2 * s2b.x;

            float nlen = fmaxf(sqrtf(nx * nx + ny * ny + nz * nz), 1e-12f);
            nx /= nlen; ny /= nlen; nz /= nlen;

            float dx = ox - px, dy = oy - py, dz = oz - pz;
            fg[k] = 1.f;
            dep[k] = sqrtf(dx * dx + dy * dy + dz * dz);
            pos[k][0] = px; pos[k][1] = py; pos[k][2] = pz;
            nrm[k][0] = nx; nrm[k][1] = ny; nrm[k][2] = nz;
            sc[k][0] = sx; sc[k][1] = sy; sc[k][2] = sz;
        } else {
            fg[k] = 0.f; dep[k] = 0.f;
            pos[k][0] = pos[k][1] = pos[k][2] = 0.f;
            nrm[k][0] = nrm[k][1] = nrm[k][2] = 0.f;
            sc[k][0] = sc[k][1] = sc[k][2] = 0.f;
        }
    }

    // stage 6 floats per plane per thread into LDS
    {
        float* L0 = &lds[0][tid * 6];
        L0[0] = fg[0]; L0[1] = fg[0]; L0[2] = fg[0];
        L0[3] = fg[1]; L0[4] = fg[1]; L0[5] = fg[1];
        float* L1 = &lds[1][tid * 6];
        L1[0] = pos[0][0]; L1[1] = pos[0][1]; L1[2] = pos[0][2];
        L1[3] = pos[1][0]; L1[4] = pos[1][1]; L1[5] = pos[1][2];
        float* L2 = &lds[2][tid * 6];
        L2[0] = nrm[0][0]; L2[1] = nrm[0][1]; L2[2] = nrm[0][2];
        L2[3] = nrm[1][0]; L2[4] = nrm[1][1]; L2[5] = nrm[1][2];
        float* L3 = &lds[3][tid * 6];
        L3[0] = dep[0]; L3[1] = dep[0]; L3[2] = dep[0];
        L3[3] = dep[1]; L3[4] = dep[1]; L3[5] = dep[1];
        float* L4 = &lds[4][tid * 6];
        L4[0] = sc[0][0]; L4[1] = sc[0][1]; L4[2] = sc[0][2];
        L4[3] = sc[1][0]; L4[4] = sc[1][1]; L4[5] = sc[1][2];
    }
    __syncthreads();

    // cooperative full-line NT stores: chunk j <-> lane j, contiguous 4KB/instr
    const int CHUNKS_PER_PLANE = PXB * 3 / 4;   // 384
    size_t blockbase = (size_t)swz * (PXB * 3); // float offset within plane
#pragma unroll
    for (int i = tid; i < 5 * CHUNKS_PER_PLANE; i += 256) {
        int plane = i / CHUNKS_PER_PLANE;
        int j = i - plane * CHUNKS_PER_PLANE;
        f32x4 v = *(const f32x4*)&lds[plane][j * 4];
        __builtin_nontemporal_store(v, (f32x4*)(out + (size_t)plane * PLANE + blockbase) + j);
    }
}

// ---------------------------------------------------------------------------
extern "C" void kernel_launch(void* const* d_in, const int* in_sizes, int n_in,
                              void* d_out, int out_size, void* d_ws, size_t ws_size,
                              hipStream_t stream) {
    const float* vertex_pos         = (const float*)d_in[0];
    const int*   faces              = (const int*)  d_in[1];
    const int*   vert_adj_faces     = (const int*)  d_in[2];
    const float* vert_adj_weights   = (const float*)d_in[3];
    const float* intrinsics         = (const float*)d_in[4];
    const float* extrinsics         = (const float*)d_in[5];
    const float* inverse_extrinsics = (const float*)d_in[6];
    const int*   face_id            = (const int*)  d_in[7];
    const float* barycentrics       = (const float*)d_in[8];
    float* out = (float*)d_out;
    char* ws = (char*)d_ws;
    const int TPB = 256;

    // layout: fn 4.8MB | faces64 1.6MB | pn16 3.2MB | scr16 6.4MB = 16.0MB
    float*              fn      = (float*)             (ws + 0);
    unsigned long long* faces64 = (unsigned long long*)(ws + 4800000);
    uint4*              pn16    = (uint4*)             (ws + 6400000);
    uint2*              scr16   = (uint2*)             (ws + 9600000);

    hipLaunchKernelGGL(k_prep1, dim3((B_ * F_ + TPB - 1) / TPB), dim3(TPB), 0, stream,
                       vertex_pos, faces, fn, faces64);
    hipLaunchKernelGGL(k_prep2, dim3((B_ * C_ * V_ + TPB - 1) / TPB), dim3(TPB), 0, stream,
                       vertex_pos, intrinsics, extrinsics, fn,
                       vert_adj_faces, vert_adj_weights, scr16, pn16);
    hipLaunchKernelGGL(k_pixel_lds, dim3(NPIX / PXB), dim3(TPB), 0, stream,
                       faces64, inverse_extrinsics, face_id, barycentrics,
                       pn16, scr16, out);
}

// Round 9
// 93.063 us; speedup vs baseline: 1.2659x; 1.0949x over previous
//
#include <hip/hip_runtime.h>
#include <hip/hip_fp16.h>

#define B_ 2
#define C_ 4
#define H_ 512
#define W_ 512
#define V_ 100000
#define F_ 200000
#define A_ 8

#define HW_   (H_ * W_)                 // 262144 = 2^18
#define NPIX  (B_ * C_ * H_ * W_)       // 2,097,152
#define PLANE ((size_t)NPIX * 3)
#define PXB   256                       // pixels per block (1 per thread)

typedef float f32x4 __attribute__((ext_vector_type(4)));

// ---------------------------------------------------------------------------
// Prep 1 (fused): face normals (B*F) + faces64 pack (F)
// ---------------------------------------------------------------------------
__global__ void k_prep1(const float* __restrict__ vertex_pos,
                        const int* __restrict__ faces,
                        float* __restrict__ face_normal,
                        unsigned long long* __restrict__ faces64) {
    int t = blockIdx.x * blockDim.x + threadIdx.x;
    if (t >= B_ * F_) return;
    int b = t / F_;
    int f = t - b * F_;
    int i0 = faces[f * 3 + 0];
    int i1 = faces[f * 3 + 1];
    int i2 = faces[f * 3 + 2];
    if (b == 0) {
        faces64[f] = (unsigned long long)(unsigned)i0 |
                     ((unsigned long long)(unsigned)i1 << 17) |
                     ((unsigned long long)(unsigned)i2 << 34);
    }
    const float* vp = vertex_pos + (size_t)b * V_ * 3;
    float p0x = vp[i0 * 3 + 0], p0y = vp[i0 * 3 + 1], p0z = vp[i0 * 3 + 2];
    float p1x = vp[i1 * 3 + 0], p1y = vp[i1 * 3 + 1], p1z = vp[i1 * 3 + 2];
    float p2x = vp[i2 * 3 + 0], p2y = vp[i2 * 3 + 1], p2z = vp[i2 * 3 + 2];
    float e1x = p1x - p0x, e1y = p1y - p0y, e1z = p1z - p0z;
    float e2x = p2x - p0x, e2y = p2y - p0y, e2z = p2z - p0z;
    face_normal[(size_t)t * 3 + 0] = e1y * e2z - e1z * e2y;
    face_normal[(size_t)t * 3 + 1] = e1z * e2x - e1x * e2z;
    face_normal[(size_t)t * 3 + 2] = e1x * e2y - e1y * e2x;
}

// ---------------------------------------------------------------------------
// Prep 2: one thread per (b,v).  Computes vertex normal (8 adj-face blend),
// fp16-packs pos+nrm, then loops over the 4 views writing one 16B record:
//   rec16[bc*V+v] = { h2(px,py), h2(pz,nx), h2(ny,nz), h2(sx,sy) }
// (scr.z is NOT stored: blended cv2 is linear in blended pos, recomputed
//  per-pixel from extrinsics row 2 since sum(bary)=1.)
// ---------------------------------------------------------------------------
__global__ void k_prep2(const float* __restrict__ vertex_pos,
                        const float* __restrict__ intrinsics,
                        const float* __restrict__ extrinsics,
                        const float* __restrict__ face_normal,
                        const int* __restrict__ vert_adj_faces,
                        const float* __restrict__ vert_adj_weights,
                        uint4* __restrict__ rec16) {
    int t = blockIdx.x * blockDim.x + threadIdx.x;
    if (t >= B_ * V_) return;
    int b = t / V_;
    int v = t - b * V_;

    // vertex normal
    const int* adj = vert_adj_faces + (size_t)v * A_;
    const float* wt = vert_adj_weights + (size_t)v * A_;
    const float* fn = face_normal + (size_t)b * F_ * 3;
    float ax = 0.f, ay = 0.f, az = 0.f;
#pragma unroll
    for (int a = 0; a < A_; ++a) {
        int f = adj[a];
        float w = wt[a];
        ax += w * fn[(size_t)f * 3 + 0];
        ay += w * fn[(size_t)f * 3 + 1];
        az += w * fn[(size_t)f * 3 + 2];
    }
    const float* p = vertex_pos + (size_t)t * 3;
    float x = p[0], y = p[1], z = p[2];
    __half2 hxy = __floats2half2_rn(x, y);
    __half2 hzn = __floats2half2_rn(z, ax);
    __half2 hnn = __floats2half2_rn(ay, az);
    unsigned int w0 = *reinterpret_cast<unsigned int*>(&hxy);
    unsigned int w1 = *reinterpret_cast<unsigned int*>(&hzn);
    unsigned int w2 = *reinterpret_cast<unsigned int*>(&hnn);

#pragma unroll
    for (int c = 0; c < C_; ++c) {
        int bc = b * C_ + c;
        const float* E = extrinsics + (size_t)bc * 12;
        float cv0 = x * E[0] + y * E[1] + z * E[2]  + E[3];
        float cv1 = x * E[4] + y * E[5] + z * E[6]  + E[7];
        float cv2 = x * E[8] + y * E[9] + z * E[10] + E[11];
        const float* K = intrinsics + (size_t)bc * 9;
        float i0 = cv0 * K[0] + cv1 * K[1] + cv2 * K[2];
        float i1 = cv0 * K[3] + cv1 * K[4] + cv2 * K[5];
        float i2 = cv0 * K[6] + cv1 * K[7] + cv2 * K[8];
        __half2 hs = __floats2half2_rn(i0 / i2, i1 / i2);
        rec16[(size_t)bc * V_ + v] =
            make_uint4(w0, w1, w2, *reinterpret_cast<unsigned int*>(&hs));
    }
}

// ---------------------------------------------------------------------------
// Pixel kernel: 1 px/thread, XCD swizzle (1 view/XCD -> 3.2MB L2 set),
// 4 gather requests per pixel (faces64 + 3x rec16 b128), LDS-staged output
// with full-line cooperative NT stores.
// ---------------------------------------------------------------------------
__global__ __launch_bounds__(256) void k_pixel(
        const unsigned long long* __restrict__ faces64,
        const float* __restrict__ inverse_extrinsics,
        const float* __restrict__ extrinsics,
        const int* __restrict__ face_id,
        const float* __restrict__ bary,
        const uint4* __restrict__ rec16,
        float* __restrict__ out) {
    __shared__ float lds[5][PXB * 3];   // 5 x 3072B = 15360B

    // 8192 blocks, 8 XCDs -> 1024 contiguous blocks per XCD = one view
    int nb = gridDim.x;
    int bid = blockIdx.x;
    int swz = (bid & 7) * (nb >> 3) + (bid >> 3);
    int tid = threadIdx.x;

    int pix = swz * PXB + tid;
    int bc = pix >> 18;                 // HW_ = 2^18 (uniform per block)
    int b  = bc >> 2;                   // C_ == 4

    const float* ie = inverse_extrinsics + (size_t)bc * 16;
    float iw = ie[15];
    float ox = ie[3] / iw, oy = ie[7] / iw, oz = ie[11] / iw;
    const float* E = extrinsics + (size_t)bc * 12;
    float e8 = E[8], e9 = E[9], e10 = E[10], e11 = E[11];

    int fid = __builtin_nontemporal_load(face_id + pix);
    const float* bp = bary + (size_t)pix * 3;
    float w0 = __builtin_nontemporal_load(bp + 0);
    float w1 = __builtin_nontemporal_load(bp + 1);
    float w2 = __builtin_nontemporal_load(bp + 2);

    float fg = 0.f, dd = 0.f;
    float px = 0.f, py = 0.f, pz = 0.f;
    float nx = 0.f, ny = 0.f, nz = 0.f;
    float sx = 0.f, sy = 0.f, sz = 0.f;

    if (fid >= 0) {
        unsigned long long f3 = faces64[fid];
        int i0 = (int)(f3 & 0x1FFFF);
        int i1 = (int)((f3 >> 17) & 0x1FFFF);
        int i2 = (int)((f3 >> 34) & 0x1FFFF);

        size_t sbase = (size_t)bc * V_;
        uint4 A  = rec16[sbase + i0];
        uint4 Bv = rec16[sbase + i1];
        uint4 Cv = rec16[sbase + i2];

        float2 af0 = __half22float2(*reinterpret_cast<__half2*>(&A.x));
        float2 af1 = __half22float2(*reinterpret_cast<__half2*>(&A.y));
        float2 af2 = __half22float2(*reinterpret_cast<__half2*>(&A.z));
        float2 af3 = __half22float2(*reinterpret_cast<__half2*>(&A.w));
        float2 bf0 = __half22float2(*reinterpret_cast<__half2*>(&Bv.x));
        float2 bf1 = __half22float2(*reinterpret_cast<__half2*>(&Bv.y));
        float2 bf2 = __half22float2(*reinterpret_cast<__half2*>(&Bv.z));
        float2 bf3 = __half22float2(*reinterpret_cast<__half2*>(&Bv.w));
        float2 cf0 = __half22float2(*reinterpret_cast<__half2*>(&Cv.x));
        float2 cf1 = __half22float2(*reinterpret_cast<__half2*>(&Cv.y));
        float2 cf2 = __half22float2(*reinterpret_cast<__half2*>(&Cv.z));
        float2 cf3 = __half22float2(*reinterpret_cast<__half2*>(&Cv.w));

        px = w0 * af0.x + w1 * bf0.x + w2 * cf0.x;
        py = w0 * af0.y + w1 * bf0.y + w2 * cf0.y;
        pz = w0 * af1.x + w1 * bf1.x + w2 * cf1.x;
        nx = w0 * af1.y + w1 * bf1.y + w2 * cf1.y;
        ny = w0 * af2.x + w1 * bf2.x + w2 * cf2.x;
        nz = w0 * af2.y + w1 * bf2.y + w2 * cf2.y;
        sx = w0 * af3.x + w1 * bf3.x + w2 * cf3.x;
        sy = w0 * af3.y + w1 * bf3.y + w2 * cf3.y;
        // blended cv2 is linear in blended pos (sum of weights == 1)
        sz = e8 * px + e9 * py + e10 * pz + e11;

        float nlen = fmaxf(sqrtf(nx * nx + ny * ny + nz * nz), 1e-12f);
        nx /= nlen; ny /= nlen; nz /= nlen;

        float dx = ox - px, dy = oy - py, dz = oz - pz;
        dd = sqrtf(dx * dx + dy * dy + dz * dz);
        fg = 1.f;
    }

    // stage 3 floats per plane into LDS (stride-3 => conflict-light)
    {
        float* L0 = &lds[0][tid * 3];
        L0[0] = fg; L0[1] = fg; L0[2] = fg;
        float* L1 = &lds[1][tid * 3];
        L1[0] = px; L1[1] = py; L1[2] = pz;
        float* L2 = &lds[2][tid * 3];
        L2[0] = nx; L2[1] = ny; L2[2] = nz;
        float* L3 = &lds[3][tid * 3];
        L3[0] = dd; L3[1] = dd; L3[2] = dd;
        float* L4 = &lds[4][tid * 3];
        L4[0] = sx; L4[1] = sy; L4[2] = sz;
    }
    __syncthreads();

    // cooperative full-line NT stores: 3KB contiguous per plane per block
    const int CHUNKS_PER_PLANE = PXB * 3 / 4;   // 192
    size_t blockbase = (size_t)swz * (PXB * 3);
    for (int i = tid; i < 5 * CHUNKS_PER_PLANE; i += 256) {
        int plane = i / CHUNKS_PER_PLANE;
        int j = i - plane * CHUNKS_PER_PLANE;
        f32x4 v = *(const f32x4*)&lds[plane][j * 4];
        __builtin_nontemporal_store(v, (f32x4*)(out + (size_t)plane * PLANE + blockbase) + j);
    }
}

// ---------------------------------------------------------------------------
extern "C" void kernel_launch(void* const* d_in, const int* in_sizes, int n_in,
                              void* d_out, int out_size, void* d_ws, size_t ws_size,
                              hipStream_t stream) {
    const float* vertex_pos         = (const float*)d_in[0];
    const int*   faces              = (const int*)  d_in[1];
    const int*   vert_adj_faces     = (const int*)  d_in[2];
    const float* vert_adj_weights   = (const float*)d_in[3];
    const float* intrinsics         = (const float*)d_in[4];
    const float* extrinsics         = (const float*)d_in[5];
    const float* inverse_extrinsics = (const float*)d_in[6];
    const int*   face_id            = (const int*)  d_in[7];
    const float* barycentrics       = (const float*)d_in[8];
    float* out = (float*)d_out;
    char* ws = (char*)d_ws;
    const int TPB = 256;

    // layout: fn 4.8MB | faces64 1.6MB | rec16 12.8MB = 19.2MB
    float*              fn      = (float*)             (ws + 0);
    unsigned long long* faces64 = (unsigned long long*)(ws + 4800000);
    uint4*              rec16   = (uint4*)             (ws + 6400000);

    hipLaunchKernelGGL(k_prep1, dim3((B_ * F_ + TPB - 1) / TPB), dim3(TPB), 0, stream,
                       vertex_pos, faces, fn, faces64);
    hipLaunchKernelGGL(k_prep2, dim3((B_ * V_ + TPB - 1) / TPB), dim3(TPB), 0, stream,
                       vertex_pos, intrinsics, extrinsics, fn,
                       vert_adj_faces, vert_adj_weights, rec16);
    hipLaunchKernelGGL(k_pixel, dim3(NPIX / PXB), dim3(TPB), 0, stream,
                       faces64, inverse_extrinsics, extrinsics, face_id, barycentrics,
                       rec16, out);
}

// Round 10
// 86.020 us; speedup vs baseline: 1.3695x; 1.0819x over previous
//
#include <hip/hip_runtime.h>
#include <hip/hip_fp16.h>
#include <string.h>

#define B_ 2
#define C_ 4
#define H_ 512
#define W_ 512
#define V_ 100000
#define F_ 200000
#define A_ 8

#define HW_   (H_ * W_)                 // 262144 = 2^18
#define NPIX  (B_ * C_ * H_ * W_)       // 2,097,152
#define PLANE ((size_t)NPIX * 3)
#define PXB   512                       // pixels per block (2 per thread)

typedef float f32x4 __attribute__((ext_vector_type(4)));

__device__ __forceinline__ float2 unpack2f(double d) {
    float2 t;
    memcpy(&t, &d, 8);
    return t;
}

// ---------------------------------------------------------------------------
// Prep 1 (fused): fp16 face normals (B*F, 8B records) + faces64 pack (F)
//   fn16[b*F+f] = uint2{ h2(nx,ny), h2(nz,0) }
// ---------------------------------------------------------------------------
__global__ void k_prep1(const float* __restrict__ vertex_pos,
                        const int* __restrict__ faces,
                        uint2* __restrict__ fn16,
                        unsigned long long* __restrict__ faces64) {
    int t = blockIdx.x * blockDim.x + threadIdx.x;
    if (t >= B_ * F_) return;
    int b = t / F_;
    int f = t - b * F_;
    int i0 = faces[f * 3 + 0];
    int i1 = faces[f * 3 + 1];
    int i2 = faces[f * 3 + 2];
    if (b == 0) {
        faces64[f] = (unsigned long long)(unsigned)i0 |
                     ((unsigned long long)(unsigned)i1 << 17) |
                     ((unsigned long long)(unsigned)i2 << 34);
    }
    const float* vp = vertex_pos + (size_t)b * V_ * 3;
    float p0x = vp[i0 * 3 + 0], p0y = vp[i0 * 3 + 1], p0z = vp[i0 * 3 + 2];
    float p1x = vp[i1 * 3 + 0], p1y = vp[i1 * 3 + 1], p1z = vp[i1 * 3 + 2];
    float p2x = vp[i2 * 3 + 0], p2y = vp[i2 * 3 + 1], p2z = vp[i2 * 3 + 2];
    float e1x = p1x - p0x, e1y = p1y - p0y, e1z = p1z - p0z;
    float e2x = p2x - p0x, e2y = p2y - p0y, e2z = p2z - p0z;
    float nx = e1y * e2z - e1z * e2y;
    float ny = e1z * e2x - e1x * e2z;
    float nz = e1x * e2y - e1y * e2x;
    __half2 h0 = __floats2half2_rn(nx, ny);
    __half2 h1 = __floats2half2_rn(nz, 0.f);
    fn16[t] = make_uint2(*reinterpret_cast<unsigned int*>(&h0),
                         *reinterpret_cast<unsigned int*>(&h1));
}

// ---------------------------------------------------------------------------
// Prep 2: one thread per (b,v).  Vertex normal from 8 fp16 fn gathers (b64),
// then loops over 4 views writing one 16B record per view:
//   rec16[bc*V+v] = { h2(px,py), h2(pz,nx), h2(ny,nz), h2(sx,sy) }
// (scr.z recomputed per-pixel from extrinsics row 2: linear in blended pos.)
// ---------------------------------------------------------------------------
__global__ void k_prep2(const float* __restrict__ vertex_pos,
                        const float* __restrict__ intrinsics,
                        const float* __restrict__ extrinsics,
                        const uint2* __restrict__ fn16,
                        const int* __restrict__ vert_adj_faces,
                        const float* __restrict__ vert_adj_weights,
                        uint4* __restrict__ rec16) {
    int t = blockIdx.x * blockDim.x + threadIdx.x;
    if (t >= B_ * V_) return;
    int b = t / V_;
    int v = t - b * V_;

    const int* adj = vert_adj_faces + (size_t)v * A_;
    const float* wt = vert_adj_weights + (size_t)v * A_;
    const uint2* fn = fn16 + (size_t)b * F_;
    float ax = 0.f, ay = 0.f, az = 0.f;
#pragma unroll
    for (int a = 0; a < A_; ++a) {
        uint2 r = fn[adj[a]];
        float w = wt[a];
        float2 n01 = __half22float2(*reinterpret_cast<__half2*>(&r.x));
        float2 n2  = __half22float2(*reinterpret_cast<__half2*>(&r.y));
        ax += w * n01.x;
        ay += w * n01.y;
        az += w * n2.x;
    }
    const float* p = vertex_pos + (size_t)t * 3;
    float x = p[0], y = p[1], z = p[2];
    __half2 hxy = __floats2half2_rn(x, y);
    __half2 hzn = __floats2half2_rn(z, ax);
    __half2 hnn = __floats2half2_rn(ay, az);
    unsigned int w0 = *reinterpret_cast<unsigned int*>(&hxy);
    unsigned int w1 = *reinterpret_cast<unsigned int*>(&hzn);
    unsigned int w2 = *reinterpret_cast<unsigned int*>(&hnn);

#pragma unroll
    for (int c = 0; c < C_; ++c) {
        int bc = b * C_ + c;
        const float* E = extrinsics + (size_t)bc * 12;
        float cv0 = x * E[0] + y * E[1] + z * E[2]  + E[3];
        float cv1 = x * E[4] + y * E[5] + z * E[6]  + E[7];
        float cv2 = x * E[8] + y * E[9] + z * E[10] + E[11];
        const float* K = intrinsics + (size_t)bc * 9;
        float i0 = cv0 * K[0] + cv1 * K[1] + cv2 * K[2];
        float i1 = cv0 * K[3] + cv1 * K[4] + cv2 * K[5];
        float i2 = cv0 * K[6] + cv1 * K[7] + cv2 * K[8];
        __half2 hs = __floats2half2_rn(i0 / i2, i1 / i2);
        rec16[(size_t)bc * V_ + v] =
            make_uint4(w0, w1, w2, *reinterpret_cast<unsigned int*>(&hs));
    }
}

// ---------------------------------------------------------------------------
// Pixel kernel: 2 px/thread, XCD swizzle (1 view/XCD -> 3.2MB L2 set),
// 4 gather requests per pixel, LDS-staged full-line NT stores.
// ---------------------------------------------------------------------------
__global__ __launch_bounds__(256) void k_pixel(
        const unsigned long long* __restrict__ faces64,
        const float* __restrict__ inverse_extrinsics,
        const float* __restrict__ extrinsics,
        const int* __restrict__ face_id,
        const float* __restrict__ bary,
        const uint4* __restrict__ rec16,
        float* __restrict__ out) {
    __shared__ float lds[5][PXB * 3];   // 5 x 6144B = 30720B

    // 4096 blocks, 8 XCDs -> 512 contiguous blocks per XCD = one view
    int nb = gridDim.x;
    int bid = blockIdx.x;
    int swz = (bid & 7) * (nb >> 3) + (bid >> 3);
    int tid = threadIdx.x;

    int base = swz * PXB + tid * 2;     // first of 2 pixels
    int bc = base >> 18;                // HW_ = 2^18 (uniform per block)

    const float* ie = inverse_extrinsics + (size_t)bc * 16;
    float iw = ie[15];
    float ox = ie[3] / iw, oy = ie[7] / iw, oz = ie[11] / iw;
    const float* E = extrinsics + (size_t)bc * 12;
    float e8 = E[8], e9 = E[9], e10 = E[10], e11 = E[11];

    long long fid2 = __builtin_nontemporal_load((const long long*)(face_id + base));
    int fidv[2] = { (int)(fid2 & 0xFFFFFFFFll), (int)(fid2 >> 32) };

    const double* bp = (const double*)(bary + (size_t)base * 3);
    float2 q0 = unpack2f(__builtin_nontemporal_load(bp + 0));
    float2 q1 = unpack2f(__builtin_nontemporal_load(bp + 1));
    float2 q2 = unpack2f(__builtin_nontemporal_load(bp + 2));
    float bw[2][3] = {{q0.x, q0.y, q1.x}, {q1.y, q2.x, q2.y}};

    float fg[2], dep[2];
    float pos[2][3], nrm[2][3], sc[2][3];

#pragma unroll
    for (int k = 0; k < 2; ++k) {
        int fid = fidv[k];
        float w0 = bw[k][0], w1 = bw[k][1], w2 = bw[k][2];
        if (fid >= 0) {
            unsigned long long f3 = faces64[fid];
            int i0 = (int)(f3 & 0x1FFFF);
            int i1 = (int)((f3 >> 17) & 0x1FFFF);
            int i2 = (int)((f3 >> 34) & 0x1FFFF);

            size_t sbase = (size_t)bc * V_;
            uint4 A  = rec16[sbase + i0];
            uint4 Bv = rec16[sbase + i1];
            uint4 Cv = rec16[sbase + i2];

            float2 af0 = __half22float2(*reinterpret_cast<__half2*>(&A.x));
            float2 af1 = __half22float2(*reinterpret_cast<__half2*>(&A.y));
            float2 af2 = __half22float2(*reinterpret_cast<__half2*>(&A.z));
            float2 af3 = __half22float2(*reinterpret_cast<__half2*>(&A.w));
            float2 bf0 = __half22float2(*reinterpret_cast<__half2*>(&Bv.x));
            float2 bf1 = __half22float2(*reinterpret_cast<__half2*>(&Bv.y));
            float2 bf2 = __half22float2(*reinterpret_cast<__half2*>(&Bv.z));
            float2 bf3 = __half22float2(*reinterpret_cast<__half2*>(&Bv.w));
            float2 cf0 = __half22float2(*reinterpret_cast<__half2*>(&Cv.x));
            float2 cf1 = __half22float2(*reinterpret_cast<__half2*>(&Cv.y));
            float2 cf2 = __half22float2(*reinterpret_cast<__half2*>(&Cv.z));
            float2 cf3 = __half22float2(*reinterpret_cast<__half2*>(&Cv.w));

            float px = w0 * af0.x + w1 * bf0.x + w2 * cf0.x;
            float py = w0 * af0.y + w1 * bf0.y + w2 * cf0.y;
            float pz = w0 * af1.x + w1 * bf1.x + w2 * cf1.x;
            float nx = w0 * af1.y + w1 * bf1.y + w2 * cf1.y;
            float ny = w0 * af2.x + w1 * bf2.x + w2 * cf2.x;
            float nz = w0 * af2.y + w1 * bf2.y + w2 * cf2.y;
            float sx = w0 * af3.x + w1 * bf3.x + w2 * cf3.x;
            float sy = w0 * af3.y + w1 * bf3.y + w2 * cf3.y;
            float sz = e8 * px + e9 * py + e10 * pz + e11;

            float nlen = fmaxf(sqrtf(nx * nx + ny * ny + nz * nz), 1e-12f);
            nx /= nlen; ny /= nlen; nz /= nlen;

            float dx = ox - px, dy = oy - py, dz = oz - pz;
            fg[k] = 1.f;
            dep[k] = sqrtf(dx * dx + dy * dy + dz * dz);
            pos[k][0] = px; pos[k][1] = py; pos[k][2] = pz;
            nrm[k][0] = nx; nrm[k][1] = ny; nrm[k][2] = nz;
            sc[k][0] = sx; sc[k][1] = sy; sc[k][2] = sz;
        } else {
            fg[k] = 0.f; dep[k] = 0.f;
            pos[k][0] = pos[k][1] = pos[k][2] = 0.f;
            nrm[k][0] = nrm[k][1] = nrm[k][2] = 0.f;
            sc[k][0] = sc[k][1] = sc[k][2] = 0.f;
        }
    }

    // stage 6 floats per plane per thread into LDS
    {
        float* L0 = &lds[0][tid * 6];
        L0[0] = fg[0]; L0[1] = fg[0]; L0[2] = fg[0];
        L0[3] = fg[1]; L0[4] = fg[1]; L0[5] = fg[1];
        float* L1 = &lds[1][tid * 6];
        L1[0] = pos[0][0]; L1[1] = pos[0][1]; L1[2] = pos[0][2];
        L1[3] = pos[1][0]; L1[4] = pos[1][1]; L1[5] = pos[1][2];
        float* L2 = &lds[2][tid * 6];
        L2[0] = nrm[0][0]; L2[1] = nrm[0][1]; L2[2] = nrm[0][2];
        L2[3] = nrm[1][0]; L2[4] = nrm[1][1]; L2[5] = nrm[1][2];
        float* L3 = &lds[3][tid * 6];
        L3[0] = dep[0]; L3[1] = dep[0]; L3[2] = dep[0];
        L3[3] = dep[1]; L3[4] = dep[1]; L3[5] = dep[1];
        float* L4 = &lds[4][tid * 6];
        L4[0] = sc[0][0]; L4[1] = sc[0][1]; L4[2] = sc[0][2];
        L4[3] = sc[1][0]; L4[4] = sc[1][1]; L4[5] = sc[1][2];
    }
    __syncthreads();

    // cooperative full-line NT stores: 6KB contiguous per plane per block
    const int CHUNKS_PER_PLANE = PXB * 3 / 4;   // 384
    size_t blockbase = (size_t)swz * (PXB * 3);
    for (int i = tid; i < 5 * CHUNKS_PER_PLANE; i += 256) {
        int plane = i / CHUNKS_PER_PLANE;
        int j = i - plane * CHUNKS_PER_PLANE;
        f32x4 v = *(const f32x4*)&lds[plane][j * 4];
        __builtin_nontemporal_store(v, (f32x4*)(out + (size_t)plane * PLANE + blockbase) + j);
    }
}

// ---------------------------------------------------------------------------
extern "C" void kernel_launch(void* const* d_in, const int* in_sizes, int n_in,
                              void* d_out, int out_size, void* d_ws, size_t ws_size,
                              hipStream_t stream) {
    const float* vertex_pos         = (const float*)d_in[0];
    const int*   faces              = (const int*)  d_in[1];
    const int*   vert_adj_faces     = (const int*)  d_in[2];
    const float* vert_adj_weights   = (const float*)d_in[3];
    const float* intrinsics         = (const float*)d_in[4];
    const float* extrinsics         = (const float*)d_in[5];
    const float* inverse_extrinsics = (const float*)d_in[6];
    const int*   face_id            = (const int*)  d_in[7];
    const float* barycentrics       = (const float*)d_in[8];
    float* out = (float*)d_out;
    char* ws = (char*)d_ws;
    const int TPB = 256;

    // layout: fn16 3.2MB | faces64 1.6MB | rec16 12.8MB = 17.6MB
    uint2*              fn16    = (uint2*)             (ws + 0);
    unsigned long long* faces64 = (unsigned long long*)(ws + 3200000);
    uint4*              rec16   = (uint4*)             (ws + 4800000);

    hipLaunchKernelGGL(k_prep1, dim3((B_ * F_ + TPB - 1) / TPB), dim3(TPB), 0, stream,
                       vertex_pos, faces, fn16, faces64);
    hipLaunchKernelGGL(k_prep2, dim3((B_ * V_ + TPB - 1) / TPB), dim3(TPB), 0, stream,
                       vertex_pos, intrinsics, extrinsics, fn16,
                       vert_adj_faces, vert_adj_weights, rec16);
    hipLaunchKernelGGL(k_pixel, dim3(NPIX / PXB), dim3(TPB), 0, stream,
                       faces64, inverse_extrinsics, extrinsics, face_id, barycentrics,
                       rec16, out);
}

// Round 11
// 80.543 us; speedup vs baseline: 1.4627x; 1.0680x over previous
//
#include <hip/hip_runtime.h>
#include <hip/hip_fp16.h>
#include <string.h>

#define B_ 2
#define C_ 4
#define H_ 512
#define W_ 512
#define V_ 100000
#define F_ 200000
#define A_ 8

#define HW_   (H_ * W_)                 // 262144 = 2^18
#define NPIX  (B_ * C_ * H_ * W_)       // 2,097,152
#define PLANE ((size_t)NPIX * 3)
#define PXB   512                       // pixels per block (2 per thread)

typedef float f32x4 __attribute__((ext_vector_type(4)));

__device__ __forceinline__ float2 unpack2f(double d) {
    float2 t;
    memcpy(&t, &d, 8);
    return t;
}

// ---------------------------------------------------------------------------
// Prep 1 (fused): fp16 face normals (B*F, 8B records) + faces64 pack (F)
// ---------------------------------------------------------------------------
__global__ void k_prep1(const float* __restrict__ vertex_pos,
                        const int* __restrict__ faces,
                        uint2* __restrict__ fn16,
                        unsigned long long* __restrict__ faces64) {
    int t = blockIdx.x * blockDim.x + threadIdx.x;
    if (t >= B_ * F_) return;
    int b = t / F_;
    int f = t - b * F_;
    int i0 = faces[f * 3 + 0];
    int i1 = faces[f * 3 + 1];
    int i2 = faces[f * 3 + 2];
    if (b == 0) {
        faces64[f] = (unsigned long long)(unsigned)i0 |
                     ((unsigned long long)(unsigned)i1 << 17) |
                     ((unsigned long long)(unsigned)i2 << 34);
    }
    const float* vp = vertex_pos + (size_t)b * V_ * 3;
    float p0x = vp[i0 * 3 + 0], p0y = vp[i0 * 3 + 1], p0z = vp[i0 * 3 + 2];
    float p1x = vp[i1 * 3 + 0], p1y = vp[i1 * 3 + 1], p1z = vp[i1 * 3 + 2];
    float p2x = vp[i2 * 3 + 0], p2y = vp[i2 * 3 + 1], p2z = vp[i2 * 3 + 2];
    float e1x = p1x - p0x, e1y = p1y - p0y, e1z = p1z - p0z;
    float e2x = p2x - p0x, e2y = p2y - p0y, e2z = p2z - p0z;
    float nx = e1y * e2z - e1z * e2y;
    float ny = e1z * e2x - e1x * e2z;
    float nz = e1x * e2y - e1y * e2x;
    __half2 h0 = __floats2half2_rn(nx, ny);
    __half2 h1 = __floats2half2_rn(nz, 0.f);
    fn16[t] = make_uint2(*reinterpret_cast<unsigned int*>(&h0),
                         *reinterpret_cast<unsigned int*>(&h1));
}

// ---------------------------------------------------------------------------
// Prep 2: one thread per (b,v).  Vertex normal from 8 fp16 fn gathers (b64),
// then 4 views x one 16B record:
//   rec16[bc*V+v] = { h2(px,py), h2(pz,nx), h2(ny,nz), h2(sx,sy) }
// (scr.z recomputed per-pixel: linear in blended pos since sum(bary)=1.)
// ---------------------------------------------------------------------------
__global__ void k_prep2(const float* __restrict__ vertex_pos,
                        const float* __restrict__ intrinsics,
                        const float* __restrict__ extrinsics,
                        const uint2* __restrict__ fn16,
                        const int* __restrict__ vert_adj_faces,
                        const float* __restrict__ vert_adj_weights,
                        uint4* __restrict__ rec16) {
    int t = blockIdx.x * blockDim.x + threadIdx.x;
    if (t >= B_ * V_) return;
    int b = t / V_;
    int v = t - b * V_;

    const int* adj = vert_adj_faces + (size_t)v * A_;
    const float* wt = vert_adj_weights + (size_t)v * A_;
    const uint2* fn = fn16 + (size_t)b * F_;
    float ax = 0.f, ay = 0.f, az = 0.f;
#pragma unroll
    for (int a = 0; a < A_; ++a) {
        uint2 r = fn[adj[a]];
        float w = wt[a];
        float2 n01 = __half22float2(*reinterpret_cast<__half2*>(&r.x));
        float2 n2  = __half22float2(*reinterpret_cast<__half2*>(&r.y));
        ax += w * n01.x;
        ay += w * n01.y;
        az += w * n2.x;
    }
    const float* p = vertex_pos + (size_t)t * 3;
    float x = p[0], y = p[1], z = p[2];
    __half2 hxy = __floats2half2_rn(x, y);
    __half2 hzn = __floats2half2_rn(z, ax);
    __half2 hnn = __floats2half2_rn(ay, az);
    unsigned int w0 = *reinterpret_cast<unsigned int*>(&hxy);
    unsigned int w1 = *reinterpret_cast<unsigned int*>(&hzn);
    unsigned int w2 = *reinterpret_cast<unsigned int*>(&hnn);

#pragma unroll
    for (int c = 0; c < C_; ++c) {
        int bc = b * C_ + c;
        const float* E = extrinsics + (size_t)bc * 12;
        float cv0 = x * E[0] + y * E[1] + z * E[2]  + E[3];
        float cv1 = x * E[4] + y * E[5] + z * E[6]  + E[7];
        float cv2 = x * E[8] + y * E[9] + z * E[10] + E[11];
        const float* K = intrinsics + (size_t)bc * 9;
        float i0 = cv0 * K[0] + cv1 * K[1] + cv2 * K[2];
        float i1 = cv0 * K[3] + cv1 * K[4] + cv2 * K[5];
        float i2 = cv0 * K[6] + cv1 * K[7] + cv2 * K[8];
        __half2 hs = __floats2half2_rn(i0 / i2, i1 / i2);
        rec16[(size_t)bc * V_ + v] =
            make_uint4(w0, w1, w2, *reinterpret_cast<unsigned int*>(&hs));
    }
}

// ---------------------------------------------------------------------------
// Pixel kernel: 2 px/thread, XCD swizzle, 4 gathers/px, plane-at-a-time LDS
// staging (6KB -> 8 blocks/CU, 32 waves) + full-line cooperative NT stores.
// ---------------------------------------------------------------------------
__global__ __launch_bounds__(256, 8) void k_pixel(
        const unsigned long long* __restrict__ faces64,
        const float* __restrict__ inverse_extrinsics,
        const float* __restrict__ extrinsics,
        const int* __restrict__ face_id,
        const float* __restrict__ bary,
        const uint4* __restrict__ rec16,
        float* __restrict__ out) {
    __shared__ float lds[PXB * 3];      // 6144 B — one plane at a time

    // 4096 blocks, 8 XCDs -> 512 contiguous blocks per XCD = one view
    int nb = gridDim.x;
    int bid = blockIdx.x;
    int swz = (bid & 7) * (nb >> 3) + (bid >> 3);
    int tid = threadIdx.x;

    int base = swz * PXB + tid * 2;     // first of 2 pixels
    int bc = base >> 18;                // HW_ = 2^18 (uniform per block)

    const float* ie = inverse_extrinsics + (size_t)bc * 16;
    float iw = ie[15];
    float ox = ie[3] / iw, oy = ie[7] / iw, oz = ie[11] / iw;
    const float* E = extrinsics + (size_t)bc * 12;
    float e8 = E[8], e9 = E[9], e10 = E[10], e11 = E[11];

    long long fid2 = __builtin_nontemporal_load((const long long*)(face_id + base));
    int fidv[2] = { (int)(fid2 & 0xFFFFFFFFll), (int)(fid2 >> 32) };

    const double* bp = (const double*)(bary + (size_t)base * 3);
    float2 q0 = unpack2f(__builtin_nontemporal_load(bp + 0));
    float2 q1 = unpack2f(__builtin_nontemporal_load(bp + 1));
    float2 q2 = unpack2f(__builtin_nontemporal_load(bp + 2));
    float bw[2][3] = {{q0.x, q0.y, q1.x}, {q1.y, q2.x, q2.y}};

    float fg[2], dep[2];
    float pos[2][3], nrm[2][3], sc[2][3];

#pragma unroll
    for (int k = 0; k < 2; ++k) {
        int fid = fidv[k];
        float w0 = bw[k][0], w1 = bw[k][1], w2 = bw[k][2];
        if (fid >= 0) {
            unsigned long long f3 = faces64[fid];
            int i0 = (int)(f3 & 0x1FFFF);
            int i1 = (int)((f3 >> 17) & 0x1FFFF);
            int i2 = (int)((f3 >> 34) & 0x1FFFF);

            size_t sbase = (size_t)bc * V_;
            uint4 A  = rec16[sbase + i0];
            uint4 Bv = rec16[sbase + i1];
            uint4 Cv = rec16[sbase + i2];

            float2 af0 = __half22float2(*reinterpret_cast<__half2*>(&A.x));
            float2 af1 = __half22float2(*reinterpret_cast<__half2*>(&A.y));
            float2 af2 = __half22float2(*reinterpret_cast<__half2*>(&A.z));
            float2 af3 = __half22float2(*reinterpret_cast<__half2*>(&A.w));
            float2 bf0 = __half22float2(*reinterpret_cast<__half2*>(&Bv.x));
            float2 bf1 = __half22float2(*reinterpret_cast<__half2*>(&Bv.y));
            float2 bf2 = __half22float2(*reinterpret_cast<__half2*>(&Bv.z));
            float2 bf3 = __half22float2(*reinterpret_cast<__half2*>(&Bv.w));
            float2 cf0 = __half22float2(*reinterpret_cast<__half2*>(&Cv.x));
            float2 cf1 = __half22float2(*reinterpret_cast<__half2*>(&Cv.y));
            float2 cf2 = __half22float2(*reinterpret_cast<__half2*>(&Cv.z));
            float2 cf3 = __half22float2(*reinterpret_cast<__half2*>(&Cv.w));

            float px = w0 * af0.x + w1 * bf0.x + w2 * cf0.x;
            float py = w0 * af0.y + w1 * bf0.y + w2 * cf0.y;
            float pz = w0 * af1.x + w1 * bf1.x + w2 * cf1.x;
            float nx = w0 * af1.y + w1 * bf1.y + w2 * cf1.y;
            float ny = w0 * af2.x + w1 * bf2.x + w2 * cf2.x;
            float nz = w0 * af2.y + w1 * bf2.y + w2 * cf2.y;
            float sx = w0 * af3.x + w1 * bf3.x + w2 * cf3.x;
            float sy = w0 * af3.y + w1 * bf3.y + w2 * cf3.y;
            float sz = e8 * px + e9 * py + e10 * pz + e11;

            float nlen = fmaxf(sqrtf(nx * nx + ny * ny + nz * nz), 1e-12f);
            nx /= nlen; ny /= nlen; nz /= nlen;

            float dx = ox - px, dy = oy - py, dz = oz - pz;
            fg[k] = 1.f;
            dep[k] = sqrtf(dx * dx + dy * dy + dz * dz);
            pos[k][0] = px; pos[k][1] = py; pos[k][2] = pz;
            nrm[k][0] = nx; nrm[k][1] = ny; nrm[k][2] = nz;
            sc[k][0] = sx; sc[k][1] = sy; sc[k][2] = sz;
        } else {
            fg[k] = 0.f; dep[k] = 0.f;
            pos[k][0] = pos[k][1] = pos[k][2] = 0.f;
            nrm[k][0] = nrm[k][1] = nrm[k][2] = 0.f;
            sc[k][0] = sc[k][1] = sc[k][2] = 0.f;
        }
    }

    // plane-at-a-time: stage 6 floats -> sync -> full-line NT store -> sync
    const int CHUNKS = PXB * 3 / 4;     // 384 chunks of 16B
    size_t blockbase = (size_t)swz * (PXB * 3);
    float* Lt = &lds[tid * 6];

#define EMIT_PLANE(P, V0, V1, V2, V3, V4, V5)                                   \
    {                                                                           \
        Lt[0] = (V0); Lt[1] = (V1); Lt[2] = (V2);                               \
        Lt[3] = (V3); Lt[4] = (V4); Lt[5] = (V5);                               \
        __syncthreads();                                                        \
        float* dst = out + (size_t)(P) * PLANE + blockbase;                     \
        for (int j = tid; j < CHUNKS; j += 256) {                               \
            f32x4 v = *(const f32x4*)&lds[j * 4];                               \
            __builtin_nontemporal_store(v, (f32x4*)dst + j);                    \
        }                                                                       \
        __syncthreads();                                                        \
    }

    EMIT_PLANE(0, fg[0], fg[0], fg[0], fg[1], fg[1], fg[1])
    EMIT_PLANE(1, pos[0][0], pos[0][1], pos[0][2], pos[1][0], pos[1][1], pos[1][2])
    EMIT_PLANE(2, nrm[0][0], nrm[0][1], nrm[0][2], nrm[1][0], nrm[1][1], nrm[1][2])
    EMIT_PLANE(3, dep[0], dep[0], dep[0], dep[1], dep[1], dep[1])
    EMIT_PLANE(4, sc[0][0], sc[0][1], sc[0][2], sc[1][0], sc[1][1], sc[1][2])
#undef EMIT_PLANE
}

// ---------------------------------------------------------------------------
extern "C" void kernel_launch(void* const* d_in, const int* in_sizes, int n_in,
                              void* d_out, int out_size, void* d_ws, size_t ws_size,
                              hipStream_t stream) {
    const float* vertex_pos         = (const float*)d_in[0];
    const int*   faces              = (const int*)  d_in[1];
    const int*   vert_adj_faces     = (const int*)  d_in[2];
    const float* vert_adj_weights   = (const float*)d_in[3];
    const float* intrinsics         = (const float*)d_in[4];
    const float* extrinsics         = (const float*)d_in[5];
    const float* inverse_extrinsics = (const float*)d_in[6];
    const int*   face_id            = (const int*)  d_in[7];
    const float* barycentrics       = (const float*)d_in[8];
    float* out = (float*)d_out;
    char* ws = (char*)d_ws;
    const int TPB = 256;

    // layout: fn16 3.2MB | faces64 1.6MB | rec16 12.8MB = 17.6MB
    uint2*              fn16    = (uint2*)             (ws + 0);
    unsigned long long* faces64 = (unsigned long long*)(ws + 3200000);
    uint4*              rec16   = (uint4*)             (ws + 4800000);

    hipLaunchKernelGGL(k_prep1, dim3((B_ * F_ + TPB - 1) / TPB), dim3(TPB), 0, stream,
                       vertex_pos, faces, fn16, faces64);
    hipLaunchKernelGGL(k_prep2, dim3((B_ * V_ + TPB - 1) / TPB), dim3(TPB), 0, stream,
                       vertex_pos, intrinsics, extrinsics, fn16,
                       vert_adj_faces, vert_adj_weights, rec16);
    hipLaunchKernelGGL(k_pixel, dim3(NPIX / PXB), dim3(TPB), 0, stream,
                       faces64, inverse_extrinsics, extrinsics, face_id, barycentrics,
                       rec16, out);
}